// Round 11
// baseline (538.377 us; speedup 1.0000x reference)
//
#include <hip/hip_runtime.h>
#include <hip/hip_bf16.h>

#define H 64
#define OUTD 20
#define NGRAPH 8
#define CAP 64     // col slots per node (max deg ~40; checked in fill)
#define NB 128     // buckets (1024 nodes each covers N<=131072)

typedef __attribute__((ext_vector_type(8))) short bf16x8;
typedef __attribute__((ext_vector_type(4))) float f32x4;
typedef __attribute__((ext_vector_type(8))) unsigned short u16x8;

// Load a harness-provided float parameter: dtype decided at runtime by flag
// (1 => float32, 0 => bf16). Branch is wave-uniform.
__device__ __forceinline__ float ldp(const void* p, int i, bool f32) {
    return f32 ? ((const float*)p)[i]
               : __bfloat162float(((const __hip_bfloat16*)p)[i]);
}

__device__ __forceinline__ float bfu(unsigned short u) {
    union { unsigned int i; float f; } c; c.i = ((unsigned)u) << 16; return c.f;
}
__device__ __forceinline__ unsigned short fbits(float f) {
    __hip_bfloat16 b = __float2bfloat16(f);
    return *reinterpret_cast<unsigned short*>(&b);
}

// ---------------- dtype detection (sampled) ----------------
__global__ void detect_dtype(const unsigned short* __restrict__ xb, int n_u16,
                             int* __restrict__ flag) {
    __shared__ int sh[256];
    int t = threadIdx.x;
    int m = min(n_u16, 4096);
    int bad = 0;
    for (int i = t; i < m; i += 256) {
        unsigned e = (xb[i] >> 7) & 0xFF;
        bad += (e >= 0x90) ? 1 : 0;
    }
    sh[t] = bad;
    __syncthreads();
    for (int off = 128; off; off >>= 1) {
        if (t < off) sh[t] += sh[t + off];
        __syncthreads();
    }
    if (t == 0) *flag = (sh[0] > (m >> 4)) ? 1 : 0;  // 1 => float32
}

// ---------------- atomic-free CSR build: bucket counting sort ----------------

__global__ void bucketA_dense0(const int* __restrict__ dst, int* __restrict__ bcnt,
                               int E, int n, int nA, int EPC,
                               const void* __restrict__ x, const void* __restrict__ W,
                               const void* __restrict__ a_s, const void* __restrict__ a_d,
                               __hip_bfloat16* __restrict__ h, float* __restrict__ s,
                               float* __restrict__ d, const int* __restrict__ flagp) {
    if ((int)blockIdx.x < nA) {
        __shared__ unsigned acnt[NB];
        int t = threadIdx.x;
        for (int i = t; i < NB; i += 256) acnt[i] = 0;
        __syncthreads();
        int base = blockIdx.x * (256 * EPC) + t;
        for (int i = 0; i < EPC; ++i) {
            int e = base + i * 256;
            if (e < E) {
                int dn = dst[e];
                if ((unsigned)dn < (unsigned)n) atomicAdd(&acnt[dn >> 10], 1u);
            }
        }
        __syncthreads();
        for (int i = t; i < NB; i += 256) bcnt[blockIdx.x * NB + i] = acnt[i];
        return;
    }
    // ---- dense0: h = x @ W0 (din=3), s/d logit dots ----
    const bool f32 = (*flagp != 0);
    int idx = ((int)blockIdx.x - nA) * 256 + threadIdx.x;
    int node = idx >> 6;
    int f = idx & 63;
    if (node >= n) return;
    float acc = 0.f;
    for (int k = 0; k < 3; ++k)
        acc += ldp(x, node * 3 + k, f32) * ldp(W, k * H + f, f32);
    h[(size_t)node * H + f] = __float2bfloat16(acc);
    float sv = acc * ldp(a_s, f, f32);
    float dv = acc * ldp(a_d, f, f32);
    for (int off = 32; off; off >>= 1) {
        sv += __shfl_xor(sv, off);
        dv += __shfl_xor(dv, off);
    }
    if (f == 0) { s[node] = sv; d[node] = dv; }
}

__global__ void bucketB1(const int* __restrict__ bcnt, int* __restrict__ boff,
                         int* __restrict__ btot, int nA) {
    __shared__ int sh[256];
    int b = blockIdx.x, t = threadIdx.x;
    int v = (t < nA) ? bcnt[t * NB + b] : 0;
    sh[t] = v;
    __syncthreads();
    for (int off = 1; off < 256; off <<= 1) {
        int add = (t >= off) ? sh[t - off] : 0;
        __syncthreads();
        sh[t] += add;
        __syncthreads();
    }
    if (t < nA) boff[t * NB + b] = sh[t] - v;
    if (t == 255) btot[b] = sh[255];
}

__global__ void bucketB2(const int* __restrict__ btot, int* __restrict__ bstart) {
    __shared__ int sh[NB];
    int t = threadIdx.x;
    int v = btot[t];
    sh[t] = v;
    __syncthreads();
    for (int off = 1; off < NB; off <<= 1) {
        int add = (t >= off) ? sh[t - off] : 0;
        __syncthreads();
        sh[t] += add;
        __syncthreads();
    }
    bstart[t] = sh[t] - v;
    if (t == NB - 1) bstart[NB] = sh[NB - 1];
}

__global__ void bucketC(const int* __restrict__ src, const int* __restrict__ dst,
                        const int* __restrict__ boff, const int* __restrict__ bstart,
                        unsigned* __restrict__ ebuf, int E, int n, int EPC) {
    __shared__ int base[NB];
    __shared__ unsigned lcur[NB];
    int t = threadIdx.x;
    for (int i = t; i < NB; i += 256) {
        base[i] = bstart[i] + boff[blockIdx.x * NB + i];
        lcur[i] = 0;
    }
    __syncthreads();
    int eb = blockIdx.x * (256 * EPC) + t;
    for (int i = 0; i < EPC; ++i) {
        int e = eb + i * 256;
        if (e < E) {
            int dn = dst[e];
            if ((unsigned)dn < (unsigned)n) {
                int b = dn >> 10;
                unsigned pos = atomicAdd(&lcur[b], 1u);
                ebuf[base[b] + pos] = ((unsigned)src[e] << 10) | (unsigned)(dn & 1023);
            }
        }
    }
}

__global__ __launch_bounds__(1024) void bucketD(const unsigned* __restrict__ ebuf,
                                                const int* __restrict__ bstart,
                                                int* __restrict__ cnt,
                                                int* __restrict__ col, int n) {
    __shared__ unsigned lcnt[1024];
    int b = blockIdx.x, t = threadIdx.x;
    lcnt[t] = 0;
    __syncthreads();
    int beg = bstart[b], end = bstart[b + 1];
    for (int i = beg + t; i < end; i += 1024) {
        unsigned e = ebuf[i];
        int loc = (int)(e & 1023u);
        int sn = (int)(e >> 10);
        unsigned pos = atomicAdd(&lcnt[loc], 1u);
        if (pos < CAP) col[(size_t)((b << 10) + loc) * CAP + pos] = sn;
    }
    __syncthreads();
    int node = (b << 10) + t;
    if (node < n) cnt[node] = (int)min(lcnt[t], (unsigned)CAP);
}

// ---------------- gat for one node -> activated bf16 row into LDS ----------------
// Same verified fast path as standalone gat (oct broadcast); writes to Rrow
// (72-short padded LDS row) instead of global.

__device__ __forceinline__ void gat_node_to_lds(
    int node, int lane, const __hip_bfloat16* __restrict__ h,
    const float* __restrict__ s, const float* __restrict__ d,
    const int* __restrict__ cnt, const int* __restrict__ col,
    const void* __restrict__ bias, bool f32, int n, short* Rrow) {
    if (node >= n) {
        if (lane < 8) {
            u16x8 zz; for (int i = 0; i < 8; ++i) zz[i] = 0;
            *(u16x8*)(Rrow + lane * 8) = zz;
        }
        return;
    }
    int deg = min(cnt[node], CAP);
    int D = deg + 1;                    // + virtual self loop
    size_t base = (size_t)node * CAP;
    float di = d[node];

    if (D <= 64) {
        bool act = lane < D;
        int j = (lane < deg) ? col[base + lane] : node;
        j = ((unsigned)j < (unsigned)n) ? j : 0;
        float v = act ? s[j] + di : -INFINITY;
        v = v > 0.f ? v : 0.2f * v;
        float m = v;
        for (int off = 32; off; off >>= 1) m = fmaxf(m, __shfl_xor(m, off));
        float wgt = act ? __expf(v - m) : 0.f;
        float wsum = wgt;
        for (int off = 32; off; off >>= 1) wsum += __shfl_xor(wsum, off);

        const u16x8* h8 = (const u16x8*)h;
        int c = lane & 7, q = lane >> 3;
        float a[8] = {0.f, 0.f, 0.f, 0.f, 0.f, 0.f, 0.f, 0.f};
        int groups = (D + 7) >> 3;
        for (int p = 0; p < groups; ++p) {
            int tt = 8 * p + q;              // tt<=63 always; wgt=0 if tt>=D
            float wt = __shfl(wgt, tt);
            int jt = __shfl(j, tt);
            u16x8 hv = h8[jt * 8 + c];
            a[0] += wt * bfu(hv[0]);
            a[1] += wt * bfu(hv[1]);
            a[2] += wt * bfu(hv[2]);
            a[3] += wt * bfu(hv[3]);
            a[4] += wt * bfu(hv[4]);
            a[5] += wt * bfu(hv[5]);
            a[6] += wt * bfu(hv[6]);
            a[7] += wt * bfu(hv[7]);
        }
        for (int i = 0; i < 8; ++i) {
            a[i] += __shfl_xor(a[i], 8);
            a[i] += __shfl_xor(a[i], 16);
            a[i] += __shfl_xor(a[i], 32);
        }
        if (lane < 8) {
            float inv = 1.f / fmaxf(wsum, 1e-20f);
            u16x8 ov;
            for (int i = 0; i < 8; ++i) {
                float o = a[i] * inv + ldp(bias, 8 * c + i, f32);
                o = o > 0.f ? o : 0.01f * o;
                ov[i] = fbits(o);
            }
            *(u16x8*)(Rrow + c * 8) = ov;
        }
        return;
    }

    // generic path (deg == CAP) — practically never
    float m = -INFINITY;
    for (int e = lane; e < D; e += 64) {
        int j = (e < deg) ? col[base + e] : node;
        j = ((unsigned)j < (unsigned)n) ? j : 0;
        float v = s[j] + di;
        v = v > 0.f ? v : 0.2f * v;
        m = fmaxf(m, v);
    }
    for (int off = 32; off; off >>= 1) m = fmaxf(m, __shfl_xor(m, off));
    if (!(m > -INFINITY)) m = 0.f;

    float acc = 0.f, wsum = 0.f;
    for (int b = 0; b < D; b += 64) {
        int e = b + lane;
        float w = 0.f;
        int j = 0;
        if (e < D) {
            j = (e < deg) ? col[base + e] : node;
            j = ((unsigned)j < (unsigned)n) ? j : 0;
            float v = s[j] + di;
            v = v > 0.f ? v : 0.2f * v;
            w = __expf(v - m);
        }
        wsum += w;
        int c2 = min(64, D - b);
        for (int tt = 0; tt < c2; ++tt) {
            float wt = __shfl(w, tt);
            int jt = __shfl(j, tt);
            acc += wt * __bfloat162float(h[(size_t)jt * H + lane]);
        }
    }
    for (int off = 32; off; off >>= 1) wsum += __shfl_xor(wsum, off);

    float o = acc / fmaxf(wsum, 1e-20f) + ldp(bias, lane, f32);
    o = o > 0.f ? o : 0.01f * o;
    Rrow[lane] = (short)fbits(o);
}

// ---------------- fused: GAT layer k -> dense layer k+1 ----------------
// Block = 4 waves x 16 nodes. Wave gats its 16 nodes into LDS rows, then
// runs the MFMA dense on them (A from LDS, W^T staged in LDS).

__global__ __launch_bounds__(256) void gat_dense(
    const __hip_bfloat16* __restrict__ h,
    const float* __restrict__ s, const float* __restrict__ d,
    const int* __restrict__ cnt, const int* __restrict__ col,
    const void* __restrict__ bias,
    const void* __restrict__ W,
    const void* __restrict__ a_s, const void* __restrict__ a_d,
    __hip_bfloat16* __restrict__ hout, float* __restrict__ sout,
    float* __restrict__ dout, int n, const int* __restrict__ flagp) {
    const bool f32 = (*flagp != 0);
    __shared__ short Wt[64 * 72];   // Wt[nf][k], padded
    __shared__ short R[64 * 72];    // gat-out rows, padded
    int t = threadIdx.x;
    for (int i = t; i < 4096; i += 256) {
        int k = i >> 6, nf = i & 63;
        Wt[nf * 72 + k] = (short)fbits(ldp(W, i, f32));
    }
    __syncthreads();

    int wid = t >> 6, lane = t & 63;
    int blockBase = blockIdx.x * 64;
    short* Rw = R + (wid * 16) * 72;   // wave-private 16 rows

    for (int it = 0; it < 16; ++it)
        gat_node_to_lds(blockBase + wid * 16 + it, lane, h, s, d, cnt, col,
                        bias, f32, n, Rw + it * 72);
    __syncthreads();   // R fully written (also covers generic-path scalars)

    // ---- dense: hout = act_rows @ W ; s/d dots ----
    int quad = lane >> 4, n16 = lane & 15;
    int nodeBase = blockBase + wid * 16;
    const short* arow = R + (size_t)(wid * 16 + n16) * 72;
    bf16x8 a0 = *(const bf16x8*)(arow + quad * 8);
    bf16x8 a1 = *(const bf16x8*)(arow + 32 + quad * 8);

    float as_v[4], ad_v[4];
    for (int nt = 0; nt < 4; ++nt) {
        as_v[nt] = ldp(a_s, nt * 16 + n16, f32);
        ad_v[nt] = ldp(a_d, nt * 16 + n16, f32);
    }

    float sv[4] = {0.f, 0.f, 0.f, 0.f}, dv[4] = {0.f, 0.f, 0.f, 0.f};
    f32x4 accs[4];
    for (int nt = 0; nt < 4; ++nt) {
        const short* wrow = Wt + (nt * 16 + n16) * 72;
        bf16x8 b0 = *(const bf16x8*)(wrow + quad * 8);
        bf16x8 b1 = *(const bf16x8*)(wrow + 32 + quad * 8);
        f32x4 c = {0.f, 0.f, 0.f, 0.f};
        c = __builtin_amdgcn_mfma_f32_16x16x32_bf16(a0, b0, c, 0, 0, 0);
        c = __builtin_amdgcn_mfma_f32_16x16x32_bf16(a1, b1, c, 0, 0, 0);
        accs[nt] = c;
        for (int r = 0; r < 4; ++r) {
            sv[r] += c[r] * as_v[nt];
            dv[r] += c[r] * ad_v[nt];
        }
    }

    for (int r = 0; r < 4; ++r) {
        int node = nodeBase + quad * 4 + r;
        if (node < n) {
            __hip_bfloat16* hr = hout + (size_t)node * 64;
            for (int nt = 0; nt < 4; ++nt)
                hr[nt * 16 + n16] = __float2bfloat16(accs[nt][r]);
        }
    }
    for (int r = 0; r < 4; ++r) {
        for (int mask = 1; mask < 16; mask <<= 1) {
            sv[r] += __shfl_xor(sv[r], mask);
            dv[r] += __shfl_xor(dv[r], mask);
        }
    }
    if (n16 == 0) {
        for (int r = 0; r < 4; ++r) {
            int node = nodeBase + quad * 4 + r;
            if (node < n) { sout[node] = sv[r]; dout[node] = dv[r]; }
        }
    }
}

// ---------------- fused: GAT layer 2 -> out-projection + vn pooling ----------------

__global__ __launch_bounds__(256) void gat_proj_pool(
    const __hip_bfloat16* __restrict__ h,
    const float* __restrict__ s, const float* __restrict__ d,
    const int* __restrict__ cnt, const int* __restrict__ col,
    const void* __restrict__ bias,
    const void* __restrict__ Wp, const void* __restrict__ bp,
    void* __restrict__ out, const int* __restrict__ batch,
    float* __restrict__ vn, int n, const int* __restrict__ flagp) {
    const bool f32 = (*flagp != 0);
    __shared__ short Wt[32 * 72];    // Wt[o][k], rows 20..31 zero
    __shared__ short R[64 * 72];
    __shared__ float part[NGRAPH * H];
    int t = threadIdx.x;
    for (int i = t; i < 32 * 64; i += 256) {
        int o = i >> 6, k = i & 63;
        Wt[o * 72 + k] = (o < OUTD) ? (short)fbits(ldp(Wp, k * OUTD + o, f32)) : 0;
    }
    for (int i = t; i < NGRAPH * H; i += 256) part[i] = 0.f;
    __syncthreads();

    int wid = t >> 6, lane = t & 63;
    int blockBase = blockIdx.x * 64;
    short* Rw = R + (wid * 16) * 72;

    for (int it = 0; it < 16; ++it)
        gat_node_to_lds(blockBase + wid * 16 + it, lane, h, s, d, cnt, col,
                        bias, f32, n, Rw + it * 72);
    __syncthreads();

    // ---- proj: out0 = rows @ out_w + out_b ----
    int quad = lane >> 4, n16 = lane & 15;
    int nodeBase = blockBase + wid * 16;
    const short* arow = R + (size_t)(wid * 16 + n16) * 72;
    bf16x8 a0 = *(const bf16x8*)(arow + quad * 8);
    bf16x8 a1 = *(const bf16x8*)(arow + 32 + quad * 8);

    f32x4 acc0 = {0.f, 0.f, 0.f, 0.f}, acc1 = {0.f, 0.f, 0.f, 0.f};
    {
        const short* wrow = Wt + n16 * 72;
        bf16x8 b0 = *(const bf16x8*)(wrow + quad * 8);
        bf16x8 b1 = *(const bf16x8*)(wrow + 32 + quad * 8);
        acc0 = __builtin_amdgcn_mfma_f32_16x16x32_bf16(a0, b0, acc0, 0, 0, 0);
        acc0 = __builtin_amdgcn_mfma_f32_16x16x32_bf16(a1, b1, acc0, 0, 0, 0);
    }
    {
        const short* wrow = Wt + (16 + n16) * 72;
        bf16x8 b0 = *(const bf16x8*)(wrow + quad * 8);
        bf16x8 b1 = *(const bf16x8*)(wrow + 32 + quad * 8);
        acc1 = __builtin_amdgcn_mfma_f32_16x16x32_bf16(a0, b0, acc1, 0, 0, 0);
        acc1 = __builtin_amdgcn_mfma_f32_16x16x32_bf16(a1, b1, acc1, 0, 0, 0);
    }
    float bv0 = ldp(bp, n16, f32);
    float bv1 = (n16 < OUTD - 16) ? ldp(bp, 16 + n16, f32) : 0.f;
    for (int r = 0; r < 4; ++r) {
        int node = nodeBase + quad * 4 + r;
        if (node >= n) break;
        float o0 = acc0[r] + bv0;
        if (f32) ((float*)out)[node * OUTD + n16] = o0;
        else     ((__hip_bfloat16*)out)[node * OUTD + n16] = __float2bfloat16(o0);
        if (n16 < OUTD - 16) {
            float o1 = acc1[r] + bv1;
            if (f32) ((float*)out)[node * OUTD + 16 + n16] = o1;
            else     ((__hip_bfloat16*)out)[node * OUTD + 16 + n16] = __float2bfloat16(o1);
        }
    }

    // ---- pool: segment_sum rows by batch into part, then global atomics ----
    float acc = 0.f;
    int cur = -1;
    for (int it = 0; it < 16; ++it) {
        int node = blockBase + wid * 16 + it;
        if (node >= n) break;
        int g = batch[node];
        if (g != cur) {
            if ((unsigned)cur < NGRAPH) atomicAdd(&part[cur * H + lane], acc);
            acc = 0.f;
            cur = g;
        }
        acc += bfu((unsigned short)Rw[it * 72 + lane]);
    }
    if ((unsigned)cur < NGRAPH) atomicAdd(&part[cur * H + lane], acc);
    __syncthreads();
    for (int i = t; i < NGRAPH * H; i += 256) {
        float v = part[i];
        if (v != 0.f) atomicAdd(&vn[i], v);
    }
}

// ---------------- virtual-node MLP head (8x64, 4 layers) ----------------

__global__ void vn_mlp(const float* __restrict__ vn, const void* __restrict__ emb,
                       const void* __restrict__ w1, const void* __restrict__ b1,
                       const void* __restrict__ w2, const void* __restrict__ b2,
                       const void* __restrict__ w3, const void* __restrict__ b3,
                       const void* __restrict__ w4, const void* __restrict__ b4,
                       void* __restrict__ out, int out1_off, const int* __restrict__ flagp) {
    const bool f32 = (*flagp != 0);
    __shared__ float A[NGRAPH * H], B[NGRAPH * H];
    int t = threadIdx.x;          // 512 threads = 8 graphs x 64 feats
    int g = t >> 6, f = t & 63;
    A[t] = vn[t] + ldp(emb, f, f32);
    __syncthreads();
    float acc = ldp(b1, f, f32);
    for (int k = 0; k < H; ++k) acc += A[g * H + k] * ldp(w1, k * H + f, f32);
    B[t] = fmaxf(acc, 0.f);
    __syncthreads();
    acc = ldp(b2, f, f32);
    for (int k = 0; k < H; ++k) acc += B[g * H + k] * ldp(w2, k * H + f, f32);
    A[t] = fmaxf(acc, 0.f);
    __syncthreads();
    acc = ldp(b3, f, f32);
    for (int k = 0; k < H; ++k) acc += A[g * H + k] * ldp(w3, k * H + f, f32);
    B[t] = fmaxf(acc, 0.f);
    __syncthreads();
    if (f < OUTD) {
        acc = ldp(b4, f, f32);
        for (int k = 0; k < H; ++k) acc += B[g * H + k] * ldp(w4, k * OUTD + f, f32);
        acc = fmaxf(acc, 0.f);
        int idx = out1_off + g * OUTD + f;
        if (f32) ((float*)out)[idx] = acc;
        else     ((__hip_bfloat16*)out)[idx] = __float2bfloat16(acc);
    }
}

// ---------------- launcher ----------------

extern "C" void kernel_launch(void* const* d_in, const int* in_sizes, int n_in,
                              void* d_out, int out_size, void* d_ws, size_t ws_size,
                              hipStream_t stream) {
    const void* x   = d_in[0];
    const int* ei   = (const int*)d_in[1];
    const int* batch= (const int*)d_in[2];
    const void* W0  = d_in[3];
    const void* as0 = d_in[4];
    const void* ad0 = d_in[5];
    const void* b0  = d_in[6];
    const void* W1  = d_in[7];
    const void* as1 = d_in[8];
    const void* ad1 = d_in[9];
    const void* b1  = d_in[10];
    const void* W2  = d_in[11];
    const void* as2 = d_in[12];
    const void* ad2 = d_in[13];
    const void* b2  = d_in[14];
    const void* vne = d_in[15];
    const void* m1w1 = d_in[16];
    const void* m1b1 = d_in[17];
    const void* m1w2 = d_in[18];
    const void* m1b2 = d_in[19];
    const void* mfw1 = d_in[20];
    const void* mfb1 = d_in[21];
    const void* mfw2 = d_in[22];
    const void* mfb2 = d_in[23];
    const void* outw = d_in[24];
    const void* outb = d_in[25];

    const int N = in_sizes[2];
    const int E = in_sizes[1] / 2;
    const int* srcp = ei;
    const int* dstp = ei + E;

    // workspace carve (256B aligned) — total ~60 MB
    char* w = (char*)d_ws;
    auto alloc = [&](size_t bytes) -> void* {
        void* p = (void*)w;
        w += ((bytes + 255) / 256) * 256;
        return p;
    };
    int*   flag   = (int*)alloc(256);
    int*   bcnt   = (int*)alloc((size_t)256 * NB * 4);
    int*   boff   = (int*)alloc((size_t)256 * NB * 4);
    int*   btot   = (int*)alloc((size_t)NB * 4);
    int*   bstart = (int*)alloc((size_t)(NB + 1) * 4);
    unsigned* ebuf= (unsigned*)alloc((size_t)E * 4);
    int*   cnt    = (int*)alloc((size_t)N * 4);
    int*   col    = (int*)alloc((size_t)N * CAP * 4);
    __hip_bfloat16* hA = (__hip_bfloat16*)alloc((size_t)N * H * 2);
    __hip_bfloat16* hB = (__hip_bfloat16*)alloc((size_t)N * H * 2);
    float* sA     = (float*)alloc((size_t)N * 4);
    float* dA     = (float*)alloc((size_t)N * 4);
    float* sB     = (float*)alloc((size_t)N * 4);
    float* dB     = (float*)alloc((size_t)N * 4);
    float* vn     = (float*)alloc((size_t)NGRAPH * H * 4);

    const int nbN64 = (N * H + 255) / 256;
    const int nb64 = (N + 63) / 64;
    int EPC = 32;
    int nA = (E + 256 * EPC - 1) / (256 * EPC);
    while (nA > 256) { EPC <<= 1; nA = (E + 256 * EPC - 1) / (256 * EPC); }

    // --- dtype probe (sampled) ---
    detect_dtype<<<1, 256, 0, stream>>>((const unsigned short*)x, in_sizes[0], flag);

    // --- CSR build: atomic-free bucket counting sort (+ dense0 fused) ---
    hipMemsetAsync(vn, 0, (size_t)NGRAPH * H * 4, stream);
    bucketA_dense0<<<nA + nbN64, 256, 0, stream>>>(
        dstp, bcnt, E, N, nA, EPC, x, W0, as0, ad0, hA, sA, dA, flag);
    bucketB1<<<NB, 256, 0, stream>>>(bcnt, boff, btot, nA);
    bucketB2<<<1, NB, 0, stream>>>(btot, bstart);
    bucketC<<<nA, 256, 0, stream>>>(srcp, dstp, boff, bstart, ebuf, E, N, EPC);
    bucketD<<<NB, 1024, 0, stream>>>(ebuf, bstart, cnt, col, N);

    // --- GAT0 + dense1 ---
    gat_dense<<<nb64, 256, 0, stream>>>(hA, sA, dA, cnt, col, b0,
                                        W1, as1, ad1, hB, sB, dB, N, flag);
    // --- GAT1 + dense2 ---
    gat_dense<<<nb64, 256, 0, stream>>>(hB, sB, dB, cnt, col, b1,
                                        W2, as2, ad2, hA, sA, dA, N, flag);
    // --- GAT2 + out-projection + vn pooling ---
    gat_proj_pool<<<nb64, 256, 0, stream>>>(hA, sA, dA, cnt, col, b2,
                                            outw, outb, d_out, batch, vn, N, flag);
    // --- vn MLP head ---
    vn_mlp<<<1, 512, 0, stream>>>(vn, vne, m1w1, m1b1, m1w2, m1b2, mfw1, mfb1, mfw2, mfb2,
                                  d_out, N * OUTD, flag);
}

// Round 12
// 439.386 us; speedup vs baseline: 1.2253x; 1.2253x over previous
//
#include <hip/hip_runtime.h>
#include <hip/hip_bf16.h>

#define H 64
#define OUTD 20
#define NGRAPH 8
#define CAP 64     // col slots per node (max deg ~40; checked in fill)
#define NB 128     // buckets (1024 nodes each covers N<=131072)

typedef __attribute__((ext_vector_type(8))) short bf16x8;
typedef __attribute__((ext_vector_type(4))) float f32x4;
typedef __attribute__((ext_vector_type(8))) unsigned short u16x8;

// Load a harness-provided float parameter: dtype decided at runtime by flag
// (1 => float32, 0 => bf16). Branch is wave-uniform.
__device__ __forceinline__ float ldp(const void* p, int i, bool f32) {
    return f32 ? ((const float*)p)[i]
               : __bfloat162float(((const __hip_bfloat16*)p)[i]);
}

__device__ __forceinline__ float bfu(unsigned short u) {
    union { unsigned int i; float f; } c; c.i = ((unsigned)u) << 16; return c.f;
}
__device__ __forceinline__ unsigned short fbits(float f) {
    __hip_bfloat16 b = __float2bfloat16(f);
    return *reinterpret_cast<unsigned short*>(&b);
}

// ---------------- dtype detection (sampled) ----------------
__global__ void detect_dtype(const unsigned short* __restrict__ xb, int n_u16,
                             int* __restrict__ flag) {
    __shared__ int sh[256];
    int t = threadIdx.x;
    int m = min(n_u16, 4096);
    int bad = 0;
    for (int i = t; i < m; i += 256) {
        unsigned e = (xb[i] >> 7) & 0xFF;
        bad += (e >= 0x90) ? 1 : 0;
    }
    sh[t] = bad;
    __syncthreads();
    for (int off = 128; off; off >>= 1) {
        if (t < off) sh[t] += sh[t + off];
        __syncthreads();
    }
    if (t == 0) *flag = (sh[0] > (m >> 4)) ? 1 : 0;  // 1 => float32
}

// ---------------- atomic-free CSR build: bucket counting sort ----------------
// NOTE (measured r5-r8): ANY per-edge device-scope atomic scheme costs
// 50-110MB coherence-point write traffic regardless of sharding/ownership;
// LDS-histogram counting sort is the only cheap structure.

__global__ void bucketA_dense0(const int* __restrict__ dst, int* __restrict__ bcnt,
                               int E, int n, int nA, int EPC,
                               const void* __restrict__ x, const void* __restrict__ W,
                               const void* __restrict__ a_s, const void* __restrict__ a_d,
                               __hip_bfloat16* __restrict__ h, float* __restrict__ s,
                               float* __restrict__ d, const int* __restrict__ flagp) {
    if ((int)blockIdx.x < nA) {
        __shared__ unsigned acnt[NB];
        int t = threadIdx.x;
        for (int i = t; i < NB; i += 256) acnt[i] = 0;
        __syncthreads();
        int base = blockIdx.x * (256 * EPC) + t;
        for (int i = 0; i < EPC; ++i) {
            int e = base + i * 256;
            if (e < E) {
                int dn = dst[e];
                if ((unsigned)dn < (unsigned)n) atomicAdd(&acnt[dn >> 10], 1u);
            }
        }
        __syncthreads();
        for (int i = t; i < NB; i += 256) bcnt[blockIdx.x * NB + i] = acnt[i];
        return;
    }
    // ---- dense0: h = x @ W0 (din=3), s/d logit dots ----
    const bool f32 = (*flagp != 0);
    int idx = ((int)blockIdx.x - nA) * 256 + threadIdx.x;
    int node = idx >> 6;
    int f = idx & 63;
    if (node >= n) return;
    float acc = 0.f;
    for (int k = 0; k < 3; ++k)
        acc += ldp(x, node * 3 + k, f32) * ldp(W, k * H + f, f32);
    h[(size_t)node * H + f] = __float2bfloat16(acc);
    float sv = acc * ldp(a_s, f, f32);
    float dv = acc * ldp(a_d, f, f32);
    for (int off = 32; off; off >>= 1) {
        sv += __shfl_xor(sv, off);
        dv += __shfl_xor(dv, off);
    }
    if (f == 0) { s[node] = sv; d[node] = dv; }
}

// B1: per-bucket exclusive scan over blocks; also writes bucket totals.
__global__ void bucketB1(const int* __restrict__ bcnt, int* __restrict__ boff,
                         int* __restrict__ btot, int nA) {
    __shared__ int sh[256];
    int b = blockIdx.x, t = threadIdx.x;
    int v = (t < nA) ? bcnt[t * NB + b] : 0;
    sh[t] = v;
    __syncthreads();
    for (int off = 1; off < 256; off <<= 1) {
        int add = (t >= off) ? sh[t - off] : 0;
        __syncthreads();
        sh[t] += add;
        __syncthreads();
    }
    if (t < nA) boff[t * NB + b] = sh[t] - v;
    if (t == 255) btot[b] = sh[255];
}

// C: scatter edges into bucket-grouped ebuf (packed: src<<10 | dst&1023).
// bstart recomputed in-block from btot (cheap; saves the B2 launch).
__global__ void bucketC(const int* __restrict__ src, const int* __restrict__ dst,
                        const int* __restrict__ boff, const int* __restrict__ btot,
                        unsigned* __restrict__ ebuf, int E, int n, int EPC) {
    __shared__ int bstart[NB];
    __shared__ int base[NB];
    __shared__ unsigned lcur[NB];
    int t = threadIdx.x;
    if (t == 0) {
        int run = 0;
        for (int i = 0; i < NB; ++i) { bstart[i] = run; run += btot[i]; }
    }
    __syncthreads();
    for (int i = t; i < NB; i += 256) {
        base[i] = bstart[i] + boff[blockIdx.x * NB + i];
        lcur[i] = 0;
    }
    __syncthreads();
    int eb = blockIdx.x * (256 * EPC) + t;
    for (int i = 0; i < EPC; ++i) {
        int e = eb + i * 256;
        if (e < E) {
            int dn = dst[e];
            if ((unsigned)dn < (unsigned)n) {
                int b = dn >> 10;
                unsigned pos = atomicAdd(&lcur[b], 1u);
                ebuf[base[b] + pos] = ((unsigned)src[e] << 10) | (unsigned)(dn & 1023);
            }
        }
    }
}

// D: one block per bucket; LDS counters assign slots; col window per block
// = 256KB (L2-resident). bstart recomputed in-block from btot.
__global__ __launch_bounds__(1024) void bucketD(const unsigned* __restrict__ ebuf,
                                                const int* __restrict__ btot,
                                                int* __restrict__ cnt,
                                                int* __restrict__ col, int n) {
    __shared__ unsigned lcnt[1024];
    __shared__ int begend[2];
    int b = blockIdx.x, t = threadIdx.x;
    lcnt[t] = 0;
    if (t == 0) {
        int run = 0;
        for (int i = 0; i < b; ++i) run += btot[i];
        begend[0] = run;
        begend[1] = run + btot[b];
    }
    __syncthreads();
    int beg = begend[0], end = begend[1];
    for (int i = beg + t; i < end; i += 1024) {
        unsigned e = ebuf[i];
        int loc = (int)(e & 1023u);
        int sn = (int)(e >> 10);
        unsigned pos = atomicAdd(&lcnt[loc], 1u);
        if (pos < CAP) col[(size_t)((b << 10) + loc) * CAP + pos] = sn;
    }
    __syncthreads();
    int node = (b << 10) + t;
    if (node < n) cnt[node] = (int)min(lcnt[t], (unsigned)CAP);
}

// ---------------- dense layers 1/2 via MFMA ----------------

__global__ __launch_bounds__(256) void denseN_mfma(
    const __hip_bfloat16* __restrict__ in,
    const void* __restrict__ W,
    const void* __restrict__ a_s, const void* __restrict__ a_d,
    __hip_bfloat16* __restrict__ h, float* __restrict__ s,
    float* __restrict__ d, int n, const int* __restrict__ flagp) {
    const bool f32 = (*flagp != 0);
    __shared__ short Wt[64 * 72];   // Wt[nf][k], padded
    int t = threadIdx.x;
    for (int i = t; i < 4096; i += 256) {
        int k = i >> 6, nf = i & 63;
        Wt[nf * 72 + k] = (short)fbits(ldp(W, i, f32));
    }
    __syncthreads();

    int wid = t >> 6, lane = t & 63;
    int quad = lane >> 4, n16 = lane & 15;
    int nodeBase = blockIdx.x * 64 + wid * 16;
    int mrow = nodeBase + n16;
    int mclamp = min(mrow, n - 1);
    const short* inp = (const short*)in;
    const short* arow = inp + (size_t)mclamp * 64;
    bf16x8 a0 = *(const bf16x8*)(arow + quad * 8);        // k in [0,32)
    bf16x8 a1 = *(const bf16x8*)(arow + 32 + quad * 8);   // k in [32,64)

    float as_v[4], ad_v[4];
    for (int nt = 0; nt < 4; ++nt) {
        as_v[nt] = ldp(a_s, nt * 16 + n16, f32);
        ad_v[nt] = ldp(a_d, nt * 16 + n16, f32);
    }

    float sv[4] = {0.f, 0.f, 0.f, 0.f}, dv[4] = {0.f, 0.f, 0.f, 0.f};
    f32x4 accs[4];
    for (int nt = 0; nt < 4; ++nt) {
        const short* wrow = Wt + (nt * 16 + n16) * 72;
        bf16x8 b0 = *(const bf16x8*)(wrow + quad * 8);
        bf16x8 b1 = *(const bf16x8*)(wrow + 32 + quad * 8);
        f32x4 c = {0.f, 0.f, 0.f, 0.f};
        c = __builtin_amdgcn_mfma_f32_16x16x32_bf16(a0, b0, c, 0, 0, 0);
        c = __builtin_amdgcn_mfma_f32_16x16x32_bf16(a1, b1, c, 0, 0, 0);
        accs[nt] = c;
        for (int r = 0; r < 4; ++r) {
            sv[r] += c[r] * as_v[nt];
            dv[r] += c[r] * ad_v[nt];
        }
    }

    for (int r = 0; r < 4; ++r) {
        int node = nodeBase + quad * 4 + r;
        if (node < n) {
            __hip_bfloat16* hr = h + (size_t)node * 64;
            for (int nt = 0; nt < 4; ++nt)
                hr[nt * 16 + n16] = __float2bfloat16(accs[nt][r]);
        }
    }
    for (int r = 0; r < 4; ++r) {
        for (int mask = 1; mask < 16; mask <<= 1) {
            sv[r] += __shfl_xor(sv[r], mask);
            dv[r] += __shfl_xor(dv[r], mask);
        }
    }
    if (n16 == 0) {
        for (int r = 0; r < 4; ++r) {
            int node = nodeBase + quad * 4 + r;
            if (node < n) { s[node] = sv[r]; d[node] = dv[r]; }
        }
    }
}

// ---------------- GAT aggregation: one wave per node ----------------
// Fast path (deg<=63): oct broadcast — 8 lanes per edge, lane holds 8
// features (u16x8 = one dwordx4 load serves 8 edges).
// DO NOT serialize multiple nodes per wave (r11: 62->119us; TLP loss
// outweighs saved DRAM round-trips).

__global__ void gat_aggregate(const __hip_bfloat16* __restrict__ h,
                              const float* __restrict__ s, const float* __restrict__ d,
                              const int* __restrict__ cnt, const int* __restrict__ col,
                              const void* __restrict__ bias,
                              __hip_bfloat16* __restrict__ out, int n,
                              const int* __restrict__ flagp) {
    const bool f32 = (*flagp != 0);
    int node = (blockIdx.x * blockDim.x + threadIdx.x) >> 6;
    if (node >= n) return;
    int lane = threadIdx.x & 63;
    int deg = min(cnt[node], CAP);
    int D = deg + 1;                    // + virtual self loop
    size_t base = (size_t)node * CAP;
    float di = d[node];

    if (D <= 64) {
        bool act = lane < D;
        int j = (lane < deg) ? col[base + lane] : node;
        j = ((unsigned)j < (unsigned)n) ? j : 0;
        float v = act ? s[j] + di : -INFINITY;
        v = v > 0.f ? v : 0.2f * v;
        float m = v;
        for (int off = 32; off; off >>= 1) m = fmaxf(m, __shfl_xor(m, off));
        float wgt = act ? __expf(v - m) : 0.f;
        float wsum = wgt;
        for (int off = 32; off; off >>= 1) wsum += __shfl_xor(wsum, off);

        const u16x8* h8 = (const u16x8*)h;
        int c = lane & 7, q = lane >> 3;
        float a[8] = {0.f, 0.f, 0.f, 0.f, 0.f, 0.f, 0.f, 0.f};
        int groups = (D + 7) >> 3;
        for (int p = 0; p < groups; ++p) {
            int t = 8 * p + q;               // t<=63 always; wgt=0 if t>=D
            float wt = __shfl(wgt, t);
            int jt = __shfl(j, t);
            u16x8 hv = h8[jt * 8 + c];
            a[0] += wt * bfu(hv[0]);
            a[1] += wt * bfu(hv[1]);
            a[2] += wt * bfu(hv[2]);
            a[3] += wt * bfu(hv[3]);
            a[4] += wt * bfu(hv[4]);
            a[5] += wt * bfu(hv[5]);
            a[6] += wt * bfu(hv[6]);
            a[7] += wt * bfu(hv[7]);
        }
        for (int i = 0; i < 8; ++i) {
            a[i] += __shfl_xor(a[i], 8);
            a[i] += __shfl_xor(a[i], 16);
            a[i] += __shfl_xor(a[i], 32);
        }
        if (lane < 8) {
            float inv = 1.f / fmaxf(wsum, 1e-20f);
            u16x8 ov;
            for (int i = 0; i < 8; ++i) {
                float o = a[i] * inv + ldp(bias, 8 * c + i, f32);
                o = o > 0.f ? o : 0.01f * o;
                ov[i] = fbits(o);
            }
            ((u16x8*)out)[(size_t)node * 8 + c] = ov;
        }
        return;
    }

    // generic path (deg == CAP) — practically never
    float m = -INFINITY;
    for (int e = lane; e < D; e += 64) {
        int j = (e < deg) ? col[base + e] : node;
        j = ((unsigned)j < (unsigned)n) ? j : 0;
        float v = s[j] + di;
        v = v > 0.f ? v : 0.2f * v;
        m = fmaxf(m, v);
    }
    for (int off = 32; off; off >>= 1) m = fmaxf(m, __shfl_xor(m, off));
    if (!(m > -INFINITY)) m = 0.f;

    float acc = 0.f, wsum = 0.f;
    for (int b = 0; b < D; b += 64) {
        int e = b + lane;
        float w = 0.f;
        int j = 0;
        if (e < D) {
            j = (e < deg) ? col[base + e] : node;
            j = ((unsigned)j < (unsigned)n) ? j : 0;
            float v = s[j] + di;
            v = v > 0.f ? v : 0.2f * v;
            w = __expf(v - m);
        }
        wsum += w;
        int c2 = min(64, D - b);
        for (int t = 0; t < c2; ++t) {
            float wt = __shfl(w, t);
            int jt = __shfl(j, t);
            acc += wt * __bfloat162float(h[(size_t)jt * H + lane]);
        }
    }
    for (int off = 32; off; off >>= 1) wsum += __shfl_xor(wsum, off);

    float o = acc / fmaxf(wsum, 1e-20f) + ldp(bias, lane, f32);
    o = o > 0.f ? o : 0.01f * o;
    out[(size_t)node * H + lane] = __float2bfloat16(o);
}

// ---------------- fused: MFMA node projection + vn pooling ----------------

__global__ __launch_bounds__(256) void proj_pool(
    const __hip_bfloat16* __restrict__ h,
    const void* __restrict__ W, const void* __restrict__ b,
    void* __restrict__ out, int n, const int* __restrict__ flagp,
    int projBlocks, const int* __restrict__ batch, float* __restrict__ vn) {
    const bool f32 = (*flagp != 0);
    if ((int)blockIdx.x < projBlocks) {
        __shared__ short Wt[32 * 72];   // Wt[o][k], rows 20..31 zero
        int t = threadIdx.x;
        for (int i = t; i < 32 * 64; i += 256) {
            int o = i >> 6, k = i & 63;
            Wt[o * 72 + k] = (o < OUTD) ? (short)fbits(ldp(W, k * OUTD + o, f32)) : 0;
        }
        __syncthreads();

        int wid = t >> 6, lane = t & 63;
        int quad = lane >> 4, n16 = lane & 15;
        int nodeBase = blockIdx.x * 64 + wid * 16;
        int mclamp = min(nodeBase + n16, n - 1);
        const short* arow = (const short*)h + (size_t)mclamp * 64;
        bf16x8 a0 = *(const bf16x8*)(arow + quad * 8);
        bf16x8 a1 = *(const bf16x8*)(arow + 32 + quad * 8);

        f32x4 acc0 = {0.f, 0.f, 0.f, 0.f}, acc1 = {0.f, 0.f, 0.f, 0.f};
        {
            const short* wrow = Wt + n16 * 72;
            bf16x8 b0 = *(const bf16x8*)(wrow + quad * 8);
            bf16x8 b1 = *(const bf16x8*)(wrow + 32 + quad * 8);
            acc0 = __builtin_amdgcn_mfma_f32_16x16x32_bf16(a0, b0, acc0, 0, 0, 0);
            acc0 = __builtin_amdgcn_mfma_f32_16x16x32_bf16(a1, b1, acc0, 0, 0, 0);
        }
        {
            const short* wrow = Wt + (16 + n16) * 72;
            bf16x8 b0 = *(const bf16x8*)(wrow + quad * 8);
            bf16x8 b1 = *(const bf16x8*)(wrow + 32 + quad * 8);
            acc1 = __builtin_amdgcn_mfma_f32_16x16x32_bf16(a0, b0, acc1, 0, 0, 0);
            acc1 = __builtin_amdgcn_mfma_f32_16x16x32_bf16(a1, b1, acc1, 0, 0, 0);
        }
        float bv0 = ldp(b, n16, f32);
        float bv1 = (n16 < OUTD - 16) ? ldp(b, 16 + n16, f32) : 0.f;
        for (int r = 0; r < 4; ++r) {
            int node = nodeBase + quad * 4 + r;
            if (node >= n) break;
            float o0 = acc0[r] + bv0;
            if (f32) ((float*)out)[node * OUTD + n16] = o0;
            else     ((__hip_bfloat16*)out)[node * OUTD + n16] = __float2bfloat16(o0);
            if (n16 < OUTD - 16) {
                float o1 = acc1[r] + bv1;
                if (f32) ((float*)out)[node * OUTD + 16 + n16] = o1;
                else     ((__hip_bfloat16*)out)[node * OUTD + 16 + n16] = __float2bfloat16(o1);
            }
        }
        return;
    }
    // ---- pooling part ----
    __shared__ float part[NGRAPH * H];
    int t = threadIdx.x;
    for (int i = t; i < NGRAPH * H; i += 256) part[i] = 0.f;
    __syncthreads();
    int pb = (int)blockIdx.x - projBlocks;
    int npb = gridDim.x - projBlocks;
    int wid = t >> 6, lane = t & 63;
    int gwave = pb * 4 + wid;
    int nwaves = npb * 4;
    int chunk = (n + nwaves - 1) / nwaves;
    int beg = gwave * chunk;
    int end = min(n, beg + chunk);
    if (beg < end) {
        float acc = 0.f;
        int cur = batch[beg];
        for (int i = beg; i < end; ++i) {
            int g = batch[i];
            if (g != cur) {
                if ((unsigned)cur < NGRAPH) atomicAdd(&part[cur * H + lane], acc);
                acc = 0.f;
                cur = g;
            }
            acc += __bfloat162float(h[(size_t)i * H + lane]);
        }
        if ((unsigned)cur < NGRAPH) atomicAdd(&part[cur * H + lane], acc);
    }
    __syncthreads();
    for (int i = t; i < NGRAPH * H; i += 256) {
        float v = part[i];
        if (v != 0.f) atomicAdd(&vn[i], v);
    }
}

// ---------------- virtual-node MLP head (8x64, 4 layers) ----------------

__global__ void vn_mlp(const float* __restrict__ vn, const void* __restrict__ emb,
                       const void* __restrict__ w1, const void* __restrict__ b1,
                       const void* __restrict__ w2, const void* __restrict__ b2,
                       const void* __restrict__ w3, const void* __restrict__ b3,
                       const void* __restrict__ w4, const void* __restrict__ b4,
                       void* __restrict__ out, int out1_off, const int* __restrict__ flagp) {
    const bool f32 = (*flagp != 0);
    __shared__ float A[NGRAPH * H], B[NGRAPH * H];
    int t = threadIdx.x;          // 512 threads = 8 graphs x 64 feats
    int g = t >> 6, f = t & 63;
    A[t] = vn[t] + ldp(emb, f, f32);
    __syncthreads();
    float acc = ldp(b1, f, f32);
    for (int k = 0; k < H; ++k) acc += A[g * H + k] * ldp(w1, k * H + f, f32);
    B[t] = fmaxf(acc, 0.f);
    __syncthreads();
    acc = ldp(b2, f, f32);
    for (int k = 0; k < H; ++k) acc += B[g * H + k] * ldp(w2, k * H + f, f32);
    A[t] = fmaxf(acc, 0.f);
    __syncthreads();
    acc = ldp(b3, f, f32);
    for (int k = 0; k < H; ++k) acc += A[g * H + k] * ldp(w3, k * H + f, f32);
    B[t] = fmaxf(acc, 0.f);
    __syncthreads();
    if (f < OUTD) {
        acc = ldp(b4, f, f32);
        for (int k = 0; k < H; ++k) acc += B[g * H + k] * ldp(w4, k * OUTD + f, f32);
        acc = fmaxf(acc, 0.f);
        int idx = out1_off + g * OUTD + f;
        if (f32) ((float*)out)[idx] = acc;
        else     ((__hip_bfloat16*)out)[idx] = __float2bfloat16(acc);
    }
}

// ---------------- launcher ----------------

extern "C" void kernel_launch(void* const* d_in, const int* in_sizes, int n_in,
                              void* d_out, int out_size, void* d_ws, size_t ws_size,
                              hipStream_t stream) {
    const void* x   = d_in[0];
    const int* ei   = (const int*)d_in[1];
    const int* batch= (const int*)d_in[2];
    const void* W0  = d_in[3];
    const void* as0 = d_in[4];
    const void* ad0 = d_in[5];
    const void* b0  = d_in[6];
    const void* W1  = d_in[7];
    const void* as1 = d_in[8];
    const void* ad1 = d_in[9];
    const void* b1  = d_in[10];
    const void* W2  = d_in[11];
    const void* as2 = d_in[12];
    const void* ad2 = d_in[13];
    const void* b2  = d_in[14];
    const void* vne = d_in[15];
    const void* m1w1 = d_in[16];
    const void* m1b1 = d_in[17];
    const void* m1w2 = d_in[18];
    const void* m1b2 = d_in[19];
    const void* mfw1 = d_in[20];
    const void* mfb1 = d_in[21];
    const void* mfw2 = d_in[22];
    const void* mfb2 = d_in[23];
    const void* outw = d_in[24];
    const void* outb = d_in[25];

    const int N = in_sizes[2];
    const int E = in_sizes[1] / 2;
    const int* srcp = ei;
    const int* dstp = ei + E;

    // workspace carve (256B aligned) — total ~72 MB
    char* w = (char*)d_ws;
    auto alloc = [&](size_t bytes) -> void* {
        void* p = (void*)w;
        w += ((bytes + 255) / 256) * 256;
        return p;
    };
    int*   flag   = (int*)alloc(256);
    int*   bcnt   = (int*)alloc((size_t)256 * NB * 4);
    int*   boff   = (int*)alloc((size_t)256 * NB * 4);
    int*   btot   = (int*)alloc((size_t)NB * 4);
    unsigned* ebuf= (unsigned*)alloc((size_t)E * 4);
    int*   cnt    = (int*)alloc((size_t)N * 4);
    int*   col    = (int*)alloc((size_t)N * CAP * 4);
    __hip_bfloat16* featA = (__hip_bfloat16*)alloc((size_t)N * H * 2);
    __hip_bfloat16* featB = (__hip_bfloat16*)alloc((size_t)N * H * 2);
    __hip_bfloat16* hbuf  = (__hip_bfloat16*)alloc((size_t)N * H * 2);
    float* sArr   = (float*)alloc((size_t)N * 4);
    float* dArr   = (float*)alloc((size_t)N * 4);
    float* vn     = (float*)alloc((size_t)NGRAPH * H * 4);

    const int nbN64 = (N * H + 255) / 256;
    const int nb64 = (N + 63) / 64;
    const int projBlocks = (N + 63) / 64;
    int EPC = 32;
    int nA = (E + 256 * EPC - 1) / (256 * EPC);
    while (nA > 256) { EPC <<= 1; nA = (E + 256 * EPC - 1) / (256 * EPC); }

    // --- dtype probe (sampled) ---
    detect_dtype<<<1, 256, 0, stream>>>((const unsigned short*)x, in_sizes[0], flag);

    // --- CSR build: atomic-free bucket counting sort (+ dense0 fused) ---
    hipMemsetAsync(vn, 0, (size_t)NGRAPH * H * 4, stream);
    bucketA_dense0<<<nA + nbN64, 256, 0, stream>>>(
        dstp, bcnt, E, N, nA, EPC, x, W0, as0, ad0, hbuf, sArr, dArr, flag);
    bucketB1<<<NB, 256, 0, stream>>>(bcnt, boff, btot, nA);
    bucketC<<<nA, 256, 0, stream>>>(srcp, dstp, boff, btot, ebuf, E, N, EPC);
    bucketD<<<NB, 1024, 0, stream>>>(ebuf, btot, cnt, col, N);

    // --- GAT layer 0 ---
    gat_aggregate<<<nbN64, 256, 0, stream>>>(hbuf, sArr, dArr, cnt, col, b0, featA, N, flag);
    // --- GAT layer 1 ---
    denseN_mfma<<<nb64, 256, 0, stream>>>(featA, W1, as1, ad1, hbuf, sArr, dArr, N, flag);
    gat_aggregate<<<nbN64, 256, 0, stream>>>(hbuf, sArr, dArr, cnt, col, b1, featB, N, flag);
    // --- GAT layer 2 ---
    denseN_mfma<<<nb64, 256, 0, stream>>>(featB, W2, as2, ad2, hbuf, sArr, dArr, N, flag);
    gat_aggregate<<<nbN64, 256, 0, stream>>>(hbuf, sArr, dArr, cnt, col, b2, featA, N, flag);

    // --- outputs: MFMA node projection + vn pooling fused ---
    proj_pool<<<projBlocks + 512, 256, 0, stream>>>(featA, outw, outb, d_out, N, flag,
                                                    projBlocks, batch, vn);
    vn_mlp<<<1, 512, 0, stream>>>(vn, vne, m1w1, m1b1, m1w2, m1b2, mfw1, mfb1, mfw2, mfb2,
                                  d_out, N * OUTD, flag);
}

// Round 13
// 424.820 us; speedup vs baseline: 1.2673x; 1.0343x over previous
//
#include <hip/hip_runtime.h>
#include <hip/hip_bf16.h>

#define H 64
#define OUTD 20
#define NGRAPH 8
#define CAP 64      // col slots per node (max deg ~40; checked in fill)
#define NBK 256     // max buckets, 512 nodes each (covers N<=131072)
#define CAPB 8192   // ebuf slots per bucket (mean ~6.3K, 24-sigma margin; checked)

typedef __attribute__((ext_vector_type(8))) short bf16x8;
typedef __attribute__((ext_vector_type(4))) float f32x4;
typedef __attribute__((ext_vector_type(8))) unsigned short u16x8;

// Load a harness-provided float parameter: dtype decided at runtime by flag
// (1 => float32, 0 => bf16). Branch is wave-uniform.
__device__ __forceinline__ float ldp(const void* p, int i, bool f32) {
    return f32 ? ((const float*)p)[i]
               : __bfloat162float(((const __hip_bfloat16*)p)[i]);
}

__device__ __forceinline__ float bfu(unsigned short u) {
    union { unsigned int i; float f; } c; c.i = ((unsigned)u) << 16; return c.f;
}
__device__ __forceinline__ unsigned short fbits(float f) {
    __hip_bfloat16 b = __float2bfloat16(f);
    return *reinterpret_cast<unsigned short*>(&b);
}

// ---------------- dtype detection (sampled) ----------------
__global__ void detect_dtype(const unsigned short* __restrict__ xb, int n_u16,
                             int* __restrict__ flag) {
    __shared__ int sh[256];
    int t = threadIdx.x;
    int m = min(n_u16, 4096);
    int bad = 0;
    for (int i = t; i < m; i += 256) {
        unsigned e = (xb[i] >> 7) & 0xFF;
        bad += (e >= 0x90) ? 1 : 0;
    }
    sh[t] = bad;
    __syncthreads();
    for (int off = 128; off; off >>= 1) {
        if (t < off) sh[t] += sh[t + off];
        __syncthreads();
    }
    if (t == 0) *flag = (sh[0] > (m >> 4)) ? 1 : 0;  // 1 => float32
}

// ---------------- CSR build: fixed-capacity reservation scatter ----------------
// (measured r5-r8: per-edge device atomics cost 50-110MB coherence traffic
// regardless of sharding; LDS counting + block-granular reservation is the
// only cheap structure. r13: fixed per-bucket ebuf regions kill the
// histogram+scan dispatches — one global atomic per (block,bucket) only.)
// Fused with dense0 (independent work; its 25K blocks dominate the grid).

__global__ void fillC_dense0(const int* __restrict__ src, const int* __restrict__ dst,
                             int* __restrict__ gcur, unsigned* __restrict__ ebuf,
                             int E, int n, int nC, int EPC, int nbk,
                             const void* __restrict__ x, const void* __restrict__ W,
                             const void* __restrict__ a_s, const void* __restrict__ a_d,
                             __hip_bfloat16* __restrict__ h, float* __restrict__ s,
                             float* __restrict__ d, const int* __restrict__ flagp) {
    if ((int)blockIdx.x < nC) {
        __shared__ unsigned lcnt[NBK];
        __shared__ int lbase[NBK];
        int t = threadIdx.x;
        for (int i = t; i < NBK; i += 256) lcnt[i] = 0;
        __syncthreads();
        int base = blockIdx.x * (256 * EPC) + t;
        // pass 1: count this block's edges per bucket
        for (int i = 0; i < EPC; ++i) {
            int e = base + i * 256;
            if (e < E) {
                int dn = dst[e];
                if ((unsigned)dn < (unsigned)n) atomicAdd(&lcnt[dn >> 9], 1u);
            }
        }
        __syncthreads();
        // reserve contiguous runs (one global atomic per non-empty bucket)
        for (int i = t; i < nbk; i += 256) {
            unsigned c = lcnt[i];
            lbase[i] = c ? atomicAdd(&gcur[i], (int)c) : 0;
            lcnt[i] = 0;
        }
        __syncthreads();
        // pass 2: place edges (re-read is L2-hot)
        for (int i = 0; i < EPC; ++i) {
            int e = base + i * 256;
            if (e < E) {
                int dn = dst[e];
                if ((unsigned)dn < (unsigned)n) {
                    int b = dn >> 9;
                    unsigned pos = (unsigned)lbase[b] + atomicAdd(&lcnt[b], 1u);
                    if (pos < CAPB)
                        ebuf[(size_t)b * CAPB + pos] =
                            ((unsigned)src[e] << 9) | (unsigned)(dn & 511);
                }
            }
        }
        return;
    }
    // ---- dense0: h = x @ W0 (din=3), s/d logit dots ----
    const bool f32 = (*flagp != 0);
    int idx = ((int)blockIdx.x - nC) * 256 + threadIdx.x;
    int node = idx >> 6;
    int f = idx & 63;
    if (node >= n) return;
    float acc = 0.f;
    for (int k = 0; k < 3; ++k)
        acc += ldp(x, node * 3 + k, f32) * ldp(W, k * H + f, f32);
    h[(size_t)node * H + f] = __float2bfloat16(acc);
    float sv = acc * ldp(a_s, f, f32);
    float dv = acc * ldp(a_d, f, f32);
    for (int off = 32; off; off >>= 1) {
        sv += __shfl_xor(sv, off);
        dv += __shfl_xor(dv, off);
    }
    if (f == 0) { s[node] = sv; d[node] = dv; }
}

// D: one block per bucket (512 nodes); LDS counters assign slots; col window
// per block = 128KB (L2-resident). cnt written wholesale (no memset needed).
__global__ __launch_bounds__(512) void bucketD(const unsigned* __restrict__ ebuf,
                                               const int* __restrict__ gcur,
                                               int* __restrict__ cnt,
                                               int* __restrict__ col, int n) {
    __shared__ unsigned lcnt[512];
    int b = blockIdx.x, t = threadIdx.x;
    lcnt[t] = 0;
    __syncthreads();
    int end = min(gcur[b], CAPB);
    const unsigned* reg = ebuf + (size_t)b * CAPB;
    for (int i = t; i < end; i += 512) {
        unsigned e = reg[i];
        int loc = (int)(e & 511u);
        int sn = (int)(e >> 9);
        unsigned pos = atomicAdd(&lcnt[loc], 1u);
        if (pos < CAP) col[(size_t)((b << 9) + loc) * CAP + pos] = sn;
    }
    __syncthreads();
    int node = (b << 9) + t;
    if (node < n) cnt[node] = (int)min(lcnt[t], (unsigned)CAP);
}

// ---------------- dense layers 1/2 via MFMA ----------------

__global__ __launch_bounds__(256) void denseN_mfma(
    const __hip_bfloat16* __restrict__ in,
    const void* __restrict__ W,
    const void* __restrict__ a_s, const void* __restrict__ a_d,
    __hip_bfloat16* __restrict__ h, float* __restrict__ s,
    float* __restrict__ d, int n, const int* __restrict__ flagp) {
    const bool f32 = (*flagp != 0);
    __shared__ short Wt[64 * 72];   // Wt[nf][k], padded
    int t = threadIdx.x;
    for (int i = t; i < 4096; i += 256) {
        int k = i >> 6, nf = i & 63;
        Wt[nf * 72 + k] = (short)fbits(ldp(W, i, f32));
    }
    __syncthreads();

    int wid = t >> 6, lane = t & 63;
    int quad = lane >> 4, n16 = lane & 15;
    int nodeBase = blockIdx.x * 64 + wid * 16;
    int mrow = nodeBase + n16;
    int mclamp = min(mrow, n - 1);
    const short* inp = (const short*)in;
    const short* arow = inp + (size_t)mclamp * 64;
    bf16x8 a0 = *(const bf16x8*)(arow + quad * 8);        // k in [0,32)
    bf16x8 a1 = *(const bf16x8*)(arow + 32 + quad * 8);   // k in [32,64)

    float as_v[4], ad_v[4];
    for (int nt = 0; nt < 4; ++nt) {
        as_v[nt] = ldp(a_s, nt * 16 + n16, f32);
        ad_v[nt] = ldp(a_d, nt * 16 + n16, f32);
    }

    float sv[4] = {0.f, 0.f, 0.f, 0.f}, dv[4] = {0.f, 0.f, 0.f, 0.f};
    f32x4 accs[4];
    for (int nt = 0; nt < 4; ++nt) {
        const short* wrow = Wt + (nt * 16 + n16) * 72;
        bf16x8 b0 = *(const bf16x8*)(wrow + quad * 8);
        bf16x8 b1 = *(const bf16x8*)(wrow + 32 + quad * 8);
        f32x4 c = {0.f, 0.f, 0.f, 0.f};
        c = __builtin_amdgcn_mfma_f32_16x16x32_bf16(a0, b0, c, 0, 0, 0);
        c = __builtin_amdgcn_mfma_f32_16x16x32_bf16(a1, b1, c, 0, 0, 0);
        accs[nt] = c;
        for (int r = 0; r < 4; ++r) {
            sv[r] += c[r] * as_v[nt];
            dv[r] += c[r] * ad_v[nt];
        }
    }

    for (int r = 0; r < 4; ++r) {
        int node = nodeBase + quad * 4 + r;
        if (node < n) {
            __hip_bfloat16* hr = h + (size_t)node * 64;
            for (int nt = 0; nt < 4; ++nt)
                hr[nt * 16 + n16] = __float2bfloat16(accs[nt][r]);
        }
    }
    for (int r = 0; r < 4; ++r) {
        for (int mask = 1; mask < 16; mask <<= 1) {
            sv[r] += __shfl_xor(sv[r], mask);
            dv[r] += __shfl_xor(dv[r], mask);
        }
    }
    if (n16 == 0) {
        for (int r = 0; r < 4; ++r) {
            int node = nodeBase + quad * 4 + r;
            if (node < n) { s[node] = sv[r]; d[node] = dv[r]; }
        }
    }
}

// ---------------- GAT aggregation: one wave per node ----------------
// Fast path (deg<=63): oct broadcast — 8 lanes per edge, lane holds 8
// features (u16x8 = one dwordx4 load serves 8 edges).
// DO NOT serialize multiple nodes per wave (r11: 62->119us; TLP loss
// outweighs saved DRAM round-trips). Pinned at ~61us: FETCH 92MB is the
// compulsory 8-XCD h-fill floor at 1.75 TB/s random-line BW (r10/r12).

__global__ void gat_aggregate(const __hip_bfloat16* __restrict__ h,
                              const float* __restrict__ s, const float* __restrict__ d,
                              const int* __restrict__ cnt, const int* __restrict__ col,
                              const void* __restrict__ bias,
                              __hip_bfloat16* __restrict__ out, int n,
                              const int* __restrict__ flagp) {
    const bool f32 = (*flagp != 0);
    int node = (blockIdx.x * blockDim.x + threadIdx.x) >> 6;
    if (node >= n) return;
    int lane = threadIdx.x & 63;
    int deg = min(cnt[node], CAP);
    int D = deg + 1;                    // + virtual self loop
    size_t base = (size_t)node * CAP;
    float di = d[node];

    if (D <= 64) {
        bool act = lane < D;
        int j = (lane < deg) ? col[base + lane] : node;
        j = ((unsigned)j < (unsigned)n) ? j : 0;
        float v = act ? s[j] + di : -INFINITY;
        v = v > 0.f ? v : 0.2f * v;
        float m = v;
        for (int off = 32; off; off >>= 1) m = fmaxf(m, __shfl_xor(m, off));
        float wgt = act ? __expf(v - m) : 0.f;
        float wsum = wgt;
        for (int off = 32; off; off >>= 1) wsum += __shfl_xor(wsum, off);

        const u16x8* h8 = (const u16x8*)h;
        int c = lane & 7, q = lane >> 3;
        float a[8] = {0.f, 0.f, 0.f, 0.f, 0.f, 0.f, 0.f, 0.f};
        int groups = (D + 7) >> 3;
        for (int p = 0; p < groups; ++p) {
            int t = 8 * p + q;               // t<=63 always; wgt=0 if t>=D
            float wt = __shfl(wgt, t);
            int jt = __shfl(j, t);
            u16x8 hv = h8[jt * 8 + c];
            a[0] += wt * bfu(hv[0]);
            a[1] += wt * bfu(hv[1]);
            a[2] += wt * bfu(hv[2]);
            a[3] += wt * bfu(hv[3]);
            a[4] += wt * bfu(hv[4]);
            a[5] += wt * bfu(hv[5]);
            a[6] += wt * bfu(hv[6]);
            a[7] += wt * bfu(hv[7]);
        }
        for (int i = 0; i < 8; ++i) {
            a[i] += __shfl_xor(a[i], 8);
            a[i] += __shfl_xor(a[i], 16);
            a[i] += __shfl_xor(a[i], 32);
        }
        if (lane < 8) {
            float inv = 1.f / fmaxf(wsum, 1e-20f);
            u16x8 ov;
            for (int i = 0; i < 8; ++i) {
                float o = a[i] * inv + ldp(bias, 8 * c + i, f32);
                o = o > 0.f ? o : 0.01f * o;
                ov[i] = fbits(o);
            }
            ((u16x8*)out)[(size_t)node * 8 + c] = ov;
        }
        return;
    }

    // generic path (deg == CAP) — practically never
    float m = -INFINITY;
    for (int e = lane; e < D; e += 64) {
        int j = (e < deg) ? col[base + e] : node;
        j = ((unsigned)j < (unsigned)n) ? j : 0;
        float v = s[j] + di;
        v = v > 0.f ? v : 0.2f * v;
        m = fmaxf(m, v);
    }
    for (int off = 32; off; off >>= 1) m = fmaxf(m, __shfl_xor(m, off));
    if (!(m > -INFINITY)) m = 0.f;

    float acc = 0.f, wsum = 0.f;
    for (int b = 0; b < D; b += 64) {
        int e = b + lane;
        float w = 0.f;
        int j = 0;
        if (e < D) {
            j = (e < deg) ? col[base + e] : node;
            j = ((unsigned)j < (unsigned)n) ? j : 0;
            float v = s[j] + di;
            v = v > 0.f ? v : 0.2f * v;
            w = __expf(v - m);
        }
        wsum += w;
        int c2 = min(64, D - b);
        for (int t = 0; t < c2; ++t) {
            float wt = __shfl(w, t);
            int jt = __shfl(j, t);
            acc += wt * __bfloat162float(h[(size_t)jt * H + lane]);
        }
    }
    for (int off = 32; off; off >>= 1) wsum += __shfl_xor(wsum, off);

    float o = acc / fmaxf(wsum, 1e-20f) + ldp(bias, lane, f32);
    o = o > 0.f ? o : 0.01f * o;
    out[(size_t)node * H + lane] = __float2bfloat16(o);
}

// ---------------- fused: MFMA node projection + vn pooling ----------------

__global__ __launch_bounds__(256) void proj_pool(
    const __hip_bfloat16* __restrict__ h,
    const void* __restrict__ W, const void* __restrict__ b,
    void* __restrict__ out, int n, const int* __restrict__ flagp,
    int projBlocks, const int* __restrict__ batch, float* __restrict__ vn) {
    const bool f32 = (*flagp != 0);
    if ((int)blockIdx.x < projBlocks) {
        __shared__ short Wt[32 * 72];   // Wt[o][k], rows 20..31 zero
        int t = threadIdx.x;
        for (int i = t; i < 32 * 64; i += 256) {
            int o = i >> 6, k = i & 63;
            Wt[o * 72 + k] = (o < OUTD) ? (short)fbits(ldp(W, k * OUTD + o, f32)) : 0;
        }
        __syncthreads();

        int wid = t >> 6, lane = t & 63;
        int quad = lane >> 4, n16 = lane & 15;
        int nodeBase = blockIdx.x * 64 + wid * 16;
        int mclamp = min(nodeBase + n16, n - 1);
        const short* arow = (const short*)h + (size_t)mclamp * 64;
        bf16x8 a0 = *(const bf16x8*)(arow + quad * 8);
        bf16x8 a1 = *(const bf16x8*)(arow + 32 + quad * 8);

        f32x4 acc0 = {0.f, 0.f, 0.f, 0.f}, acc1 = {0.f, 0.f, 0.f, 0.f};
        {
            const short* wrow = Wt + n16 * 72;
            bf16x8 b0 = *(const bf16x8*)(wrow + quad * 8);
            bf16x8 b1 = *(const bf16x8*)(wrow + 32 + quad * 8);
            acc0 = __builtin_amdgcn_mfma_f32_16x16x32_bf16(a0, b0, acc0, 0, 0, 0);
            acc0 = __builtin_amdgcn_mfma_f32_16x16x32_bf16(a1, b1, acc0, 0, 0, 0);
        }
        {
            const short* wrow = Wt + (16 + n16) * 72;
            bf16x8 b0 = *(const bf16x8*)(wrow + quad * 8);
            bf16x8 b1 = *(const bf16x8*)(wrow + 32 + quad * 8);
            acc1 = __builtin_amdgcn_mfma_f32_16x16x32_bf16(a0, b0, acc1, 0, 0, 0);
            acc1 = __builtin_amdgcn_mfma_f32_16x16x32_bf16(a1, b1, acc1, 0, 0, 0);
        }
        float bv0 = ldp(b, n16, f32);
        float bv1 = (n16 < OUTD - 16) ? ldp(b, 16 + n16, f32) : 0.f;
        for (int r = 0; r < 4; ++r) {
            int node = nodeBase + quad * 4 + r;
            if (node >= n) break;
            float o0 = acc0[r] + bv0;
            if (f32) ((float*)out)[node * OUTD + n16] = o0;
            else     ((__hip_bfloat16*)out)[node * OUTD + n16] = __float2bfloat16(o0);
            if (n16 < OUTD - 16) {
                float o1 = acc1[r] + bv1;
                if (f32) ((float*)out)[node * OUTD + 16 + n16] = o1;
                else     ((__hip_bfloat16*)out)[node * OUTD + 16 + n16] = __float2bfloat16(o1);
            }
        }
        return;
    }
    // ---- pooling part ----
    __shared__ float part[NGRAPH * H];
    int t = threadIdx.x;
    for (int i = t; i < NGRAPH * H; i += 256) part[i] = 0.f;
    __syncthreads();
    int pb = (int)blockIdx.x - projBlocks;
    int npb = gridDim.x - projBlocks;
    int wid = t >> 6, lane = t & 63;
    int gwave = pb * 4 + wid;
    int nwaves = npb * 4;
    int chunk = (n + nwaves - 1) / nwaves;
    int beg = gwave * chunk;
    int end = min(n, beg + chunk);
    if (beg < end) {
        float acc = 0.f;
        int cur = batch[beg];
        for (int i = beg; i < end; ++i) {
            int g = batch[i];
            if (g != cur) {
                if ((unsigned)cur < NGRAPH) atomicAdd(&part[cur * H + lane], acc);
                acc = 0.f;
                cur = g;
            }
            acc += __bfloat162float(h[(size_t)i * H + lane]);
        }
        if ((unsigned)cur < NGRAPH) atomicAdd(&part[cur * H + lane], acc);
    }
    __syncthreads();
    for (int i = t; i < NGRAPH * H; i += 256) {
        float v = part[i];
        if (v != 0.f) atomicAdd(&vn[i], v);
    }
}

// ---------------- virtual-node MLP head (8x64, 4 layers) ----------------

__global__ void vn_mlp(const float* __restrict__ vn, const void* __restrict__ emb,
                       const void* __restrict__ w1, const void* __restrict__ b1,
                       const void* __restrict__ w2, const void* __restrict__ b2,
                       const void* __restrict__ w3, const void* __restrict__ b3,
                       const void* __restrict__ w4, const void* __restrict__ b4,
                       void* __restrict__ out, int out1_off, const int* __restrict__ flagp) {
    const bool f32 = (*flagp != 0);
    __shared__ float A[NGRAPH * H], B[NGRAPH * H];
    int t = threadIdx.x;          // 512 threads = 8 graphs x 64 feats
    int g = t >> 6, f = t & 63;
    A[t] = vn[t] + ldp(emb, f, f32);
    __syncthreads();
    float acc = ldp(b1, f, f32);
    for (int k = 0; k < H; ++k) acc += A[g * H + k] * ldp(w1, k * H + f, f32);
    B[t] = fmaxf(acc, 0.f);
    __syncthreads();
    acc = ldp(b2, f, f32);
    for (int k = 0; k < H; ++k) acc += B[g * H + k] * ldp(w2, k * H + f, f32);
    A[t] = fmaxf(acc, 0.f);
    __syncthreads();
    acc = ldp(b3, f, f32);
    for (int k = 0; k < H; ++k) acc += A[g * H + k] * ldp(w3, k * H + f, f32);
    B[t] = fmaxf(acc, 0.f);
    __syncthreads();
    if (f < OUTD) {
        acc = ldp(b4, f, f32);
        for (int k = 0; k < H; ++k) acc += B[g * H + k] * ldp(w4, k * OUTD + f, f32);
        acc = fmaxf(acc, 0.f);
        int idx = out1_off + g * OUTD + f;
        if (f32) ((float*)out)[idx] = acc;
        else     ((__hip_bfloat16*)out)[idx] = __float2bfloat16(acc);
    }
}

// ---------------- launcher ----------------

extern "C" void kernel_launch(void* const* d_in, const int* in_sizes, int n_in,
                              void* d_out, int out_size, void* d_ws, size_t ws_size,
                              hipStream_t stream) {
    const void* x   = d_in[0];
    const int* ei   = (const int*)d_in[1];
    const int* batch= (const int*)d_in[2];
    const void* W0  = d_in[3];
    const void* as0 = d_in[4];
    const void* ad0 = d_in[5];
    const void* b0  = d_in[6];
    const void* W1  = d_in[7];
    const void* as1 = d_in[8];
    const void* ad1 = d_in[9];
    const void* b1  = d_in[10];
    const void* W2  = d_in[11];
    const void* as2 = d_in[12];
    const void* ad2 = d_in[13];
    const void* b2  = d_in[14];
    const void* vne = d_in[15];
    const void* m1w1 = d_in[16];
    const void* m1b1 = d_in[17];
    const void* m1w2 = d_in[18];
    const void* m1b2 = d_in[19];
    const void* mfw1 = d_in[20];
    const void* mfb1 = d_in[21];
    const void* mfw2 = d_in[22];
    const void* mfb2 = d_in[23];
    const void* outw = d_in[24];
    const void* outb = d_in[25];

    const int N = in_sizes[2];
    const int E = in_sizes[1] / 2;
    const int* srcp = ei;
    const int* dstp = ei + E;

    // workspace carve (256B aligned) — total ~70 MB
    char* w = (char*)d_ws;
    auto alloc = [&](size_t bytes) -> void* {
        void* p = (void*)w;
        w += ((bytes + 255) / 256) * 256;
        return p;
    };
    int*   flag   = (int*)alloc(256);
    int*   gcur   = (int*)alloc((size_t)NBK * 4);
    unsigned* ebuf= (unsigned*)alloc((size_t)NBK * CAPB * 4);
    int*   cnt    = (int*)alloc((size_t)N * 4);
    int*   col    = (int*)alloc((size_t)N * CAP * 4);
    __hip_bfloat16* featA = (__hip_bfloat16*)alloc((size_t)N * H * 2);
    __hip_bfloat16* featB = (__hip_bfloat16*)alloc((size_t)N * H * 2);
    __hip_bfloat16* hbuf  = (__hip_bfloat16*)alloc((size_t)N * H * 2);
    float* sArr   = (float*)alloc((size_t)N * 4);
    float* dArr   = (float*)alloc((size_t)N * 4);
    float* vn     = (float*)alloc((size_t)NGRAPH * H * 4);

    const int nbN64 = (N * H + 255) / 256;
    const int nb64 = (N + 63) / 64;
    const int projBlocks = (N + 63) / 64;
    const int nbk = (N + 511) >> 9;
    int EPC = 32;
    int nC = (E + 256 * EPC - 1) / (256 * EPC);
    while (nC > 256) { EPC <<= 1; nC = (E + 256 * EPC - 1) / (256 * EPC); }

    // --- dtype probe (sampled) ---
    detect_dtype<<<1, 256, 0, stream>>>((const unsigned short*)x, in_sizes[0], flag);

    // --- CSR build: reservation scatter (+ dense0 fused), then bucket place ---
    hipMemsetAsync(gcur, 0, (size_t)NBK * 4, stream);
    hipMemsetAsync(vn, 0, (size_t)NGRAPH * H * 4, stream);
    fillC_dense0<<<nC + nbN64, 256, 0, stream>>>(
        srcp, dstp, gcur, ebuf, E, N, nC, EPC, nbk,
        x, W0, as0, ad0, hbuf, sArr, dArr, flag);
    bucketD<<<nbk, 512, 0, stream>>>(ebuf, gcur, cnt, col, N);

    // --- GAT layer 0 ---
    gat_aggregate<<<nbN64, 256, 0, stream>>>(hbuf, sArr, dArr, cnt, col, b0, featA, N, flag);
    // --- GAT layer 1 ---
    denseN_mfma<<<nb64, 256, 0, stream>>>(featA, W1, as1, ad1, hbuf, sArr, dArr, N, flag);
    gat_aggregate<<<nbN64, 256, 0, stream>>>(hbuf, sArr, dArr, cnt, col, b1, featB, N, flag);
    // --- GAT layer 2 ---
    denseN_mfma<<<nb64, 256, 0, stream>>>(featB, W2, as2, ad2, hbuf, sArr, dArr, N, flag);
    gat_aggregate<<<nbN64, 256, 0, stream>>>(hbuf, sArr, dArr, cnt, col, b2, featA, N, flag);

    // --- outputs: MFMA node projection + vn pooling fused ---
    proj_pool<<<projBlocks + 512, 256, 0, stream>>>(featA, outw, outb, d_out, N, flag,
                                                    projBlocks, batch, vn);
    vn_mlp<<<1, 512, 0, stream>>>(vn, vne, m1w1, m1b1, m1w2, m1b2, mfw1, mfb1, mfw2, mfb2,
                                  d_out, N * OUTD, flag);
}